// Round 1
// baseline (98.363 us; speedup 1.0000x reference)
//
#include <hip/hip_runtime.h>

// Problem constants (match reference)
#define NB 8
#define NT 8
#define NO 25
#define NC 3
#define NH 192
#define NW 640
#define NP 16
#define ND 768
#define NGH 12
#define NGW 2
#define NKP (NB*NT*NO)   // 1600 keypoints
#define NK (NC*NP*NP)    // 768 (GEMM K)

#define S_STRIDE 37      // footprint LDS row stride (ncols <= 34)

// ---------------------------------------------------------------------------
// Kernel 1: ROI-align pooling. One block (256 threads) per keypoint.
// Thread tid = i*16 + j handles output bin (i=y-bin, j=x-bin).
// Footprint of the ROI is staged per-channel in LDS with coalesced loads;
// bilinear sampling then reads LDS only.
// pooled layout: [n][k], k = c*256 + i*16 + j  (matches conv_w's flat K)
// ---------------------------------------------------------------------------
__global__ __launch_bounds__(256) void pool_kernel(
    const float* __restrict__ features,   // [B][C][T][H][W]
    const float* __restrict__ keypoints,  // [N][3] (kx, ky, kr)
    float* __restrict__ pooled)           // [N][768]
{
  __shared__ float S[NH * S_STRIDE];      // footprint, one channel at a time
  __shared__ float s_ly[NP * NGH];
  __shared__ int   s_y0[NP * NGH];
  __shared__ float s_lx[NP * NGW];
  __shared__ int   s_x0[NP * NGW];

  const int n   = blockIdx.x;
  const int tid = threadIdx.x;

  const float kx = keypoints[n * 3 + 0];
  const float ky = keypoints[n * 3 + 1];
  const float kr = keypoints[n * 3 + 2];

  // Boxes exactly as reference (note: by2 uses kx — reference quirk, keep it)
  const float bx1 = fmaxf(kx - kr, 0.0f);
  const float by1 = fmaxf(ky - kr, 0.0f);
  const float bx2 = fminf(kx + kr, (float)NW);
  const float by2 = fminf(kx + kr, (float)NH);

  const float start_h = by1 - 0.5f;
  const float start_w = bx1 - 0.5f;
  const float roi_h = by2 - by1;
  const float roi_w = bx2 - bx1;
  const float bin_h = roi_h / (float)NP;
  const float bin_w = roi_w / (float)NP;
  const int gh = (int)ceilf(bin_h);       // ceil(roi_h / P)
  const int gw = (int)ceilf(bin_w);
  const float ghf = (float)max(gh, 1);
  const float gwf = (float)max(gw, 1);
  const float countf = (float)max(gh * gw, 1);

  // --- per-bin sample tables (computed once by first 224 threads) ---
  if (tid < NP * NGH) {
    const int i = tid / NGH, g = tid % NGH;
    const float c = start_h + (float)i * bin_h + ((float)g + 0.5f) * (bin_h / ghf);
    const bool valid = (g < gh) && (c >= -1.0f) && (c <= (float)NH);
    const float cc = fminf(fmaxf(c, 0.0f), (float)(NH - 1));
    const int lo = (int)floorf(cc);
    s_ly[tid] = cc - (float)lo;
    s_y0[tid] = valid ? lo : -1;
  } else if (tid < NP * NGH + NP * NGW) {
    const int t2 = tid - NP * NGH;
    const int j = t2 / NGW, g = t2 % NGW;
    const float c = start_w + (float)j * bin_w + ((float)g + 0.5f) * (bin_w / gwf);
    const bool valid = (g < gw) && (c >= -1.0f) && (c <= (float)NW);
    const float cc = fminf(fmaxf(c, 0.0f), (float)(NW - 1));
    const int lo = (int)floorf(cc);
    s_lx[t2] = cc - (float)lo;
    s_x0[t2] = valid ? lo : -1;
  }

  // --- footprint extent (uniform across block; samples monotonic in p,g) ---
  const float cy_min = start_h + 0.5f * (bin_h / ghf);
  const float cy_max = start_h + 15.0f * bin_h + ((float)(gh - 1) + 0.5f) * (bin_h / ghf);
  const float cx_min = start_w + 0.5f * (bin_w / gwf);
  const float cx_max = start_w + 15.0f * bin_w + ((float)(gw - 1) + 0.5f) * (bin_w / gwf);
  const int rmin = (int)floorf(fminf(fmaxf(cy_min, 0.0f), (float)(NH - 1)));
  const int rmax = min((int)floorf(fminf(fmaxf(cy_max, 0.0f), (float)(NH - 1))) + 1, NH - 1);
  const int cmin = (int)floorf(fminf(fmaxf(cx_min, 0.0f), (float)(NW - 1)));
  const int cmax = min((int)floorf(fminf(fmaxf(cx_max, 0.0f), (float)(NW - 1))) + 1, NW - 1);
  const int nrows = rmax - rmin + 1;      // <= 192
  const int ncols = cmax - cmin + 1;      // <= 34

  const int img  = n / NO;                // b*T + t
  const int bb   = img / NT;
  const int timg = img % NT;

  const int i = tid >> 4;
  const int j = tid & 15;

  __syncthreads();

  // Hoist this thread's table entries into registers (constant across channels)
  int   ry0a[NGH], ry1a[NGH];
  float lya[NGH];
#pragma unroll
  for (int gy = 0; gy < NGH; ++gy) {
    const int y0 = s_y0[i * NGH + gy];
    lya[gy]  = s_ly[i * NGH + gy];
    ry0a[gy] = (y0 < 0) ? -1 : (y0 - rmin);
    ry1a[gy] = (y0 < 0) ? -1 : (min(y0 + 1, NH - 1) - rmin);
  }
  int   cx0a[NGW], cx1a[NGW];
  float lxa[NGW];
#pragma unroll
  for (int gx = 0; gx < NGW; ++gx) {
    const int x0 = s_x0[j * NGW + gx];
    lxa[gx]  = s_lx[j * NGW + gx];
    cx0a[gx] = (x0 < 0) ? -1 : (x0 - cmin);
    cx1a[gx] = (x0 < 0) ? -1 : (min(x0 + 1, NW - 1) - cmin);
  }

  for (int ch = 0; ch < NC; ++ch) {
    __syncthreads();  // protect S against overwrite while prior reads in flight
    const float* __restrict__ src =
        features + (size_t)((bb * NC + ch) * NT + timg) * (NH * NW);
    const int tot = nrows * ncols;
    for (int e = tid; e < tot; e += 256) {
      const int r  = e / ncols;
      const int c2 = e - r * ncols;
      S[r * S_STRIDE + c2] = src[(rmin + r) * NW + cmin + c2];
    }
    __syncthreads();

    float acc = 0.0f;
#pragma unroll
    for (int gy = 0; gy < NGH; ++gy) {
      const int ry0 = ry0a[gy];
      if (ry0 < 0) continue;
      const int ry1 = ry1a[gy];
      const float ly = lya[gy];
      const float hy = 1.0f - ly;
#pragma unroll
      for (int gx = 0; gx < NGW; ++gx) {
        const int cx0 = cx0a[gx];
        if (cx0 < 0) continue;
        const int cx1 = cx1a[gx];
        const float lx = lxa[gx];
        const float hx = 1.0f - lx;
        const float v00 = S[ry0 * S_STRIDE + cx0];
        const float v01 = S[ry0 * S_STRIDE + cx1];
        const float v10 = S[ry1 * S_STRIDE + cx0];
        const float v11 = S[ry1 * S_STRIDE + cx1];
        acc += hy * (hx * v00 + lx * v01) + ly * (hx * v10 + lx * v11);
      }
    }
    pooled[(size_t)n * NK + ch * (NP * NP) + tid] = acc / countf;
  }
}

// ---------------------------------------------------------------------------
// Kernel 2: fp32 GEMM  out[1600][768] = A[1600][768] . Bw[768][768]^T + bias
// Both A and Bw are K-major (row-major, K contiguous). 64x64 tiles, 4x4
// micro-tiles, BK=32, k-major LDS with stride 68 (16B-aligned rows).
// ---------------------------------------------------------------------------
__global__ __launch_bounds__(256) void gemm_kernel(
    const float* __restrict__ A,     // [1600][768] pooled
    const float* __restrict__ Bw,    // [768][768]  conv_w
    const float* __restrict__ bias,  // [768]
    float* __restrict__ outp)        // [1600][768]
{
  __shared__ float As[32][68];
  __shared__ float Bs[32][68];
  const int bm = blockIdx.x * 64;
  const int bn = blockIdx.y * 64;
  const int tid = threadIdx.x;
  const int lr = tid >> 3;          // 0..31 (load row)
  const int lk = (tid & 7) << 2;    // 0,4,...,28 (load k offset)
  const int tm = (tid >> 4) << 2;   // 0..60
  const int tn = (tid & 15) << 2;   // 0..60

  float acc[4][4] = {};

  for (int k0 = 0; k0 < NK; k0 += 32) {
    __syncthreads();
    const float4 a0 = *reinterpret_cast<const float4*>(&A[(size_t)(bm + lr) * NK + k0 + lk]);
    const float4 a1 = *reinterpret_cast<const float4*>(&A[(size_t)(bm + lr + 32) * NK + k0 + lk]);
    const float4 b0 = *reinterpret_cast<const float4*>(&Bw[(size_t)(bn + lr) * NK + k0 + lk]);
    const float4 b1 = *reinterpret_cast<const float4*>(&Bw[(size_t)(bn + lr + 32) * NK + k0 + lk]);
    As[lk + 0][lr] = a0.x; As[lk + 1][lr] = a0.y; As[lk + 2][lr] = a0.z; As[lk + 3][lr] = a0.w;
    As[lk + 0][lr + 32] = a1.x; As[lk + 1][lr + 32] = a1.y; As[lk + 2][lr + 32] = a1.z; As[lk + 3][lr + 32] = a1.w;
    Bs[lk + 0][lr] = b0.x; Bs[lk + 1][lr] = b0.y; Bs[lk + 2][lr] = b0.z; Bs[lk + 3][lr] = b0.w;
    Bs[lk + 0][lr + 32] = b1.x; Bs[lk + 1][lr + 32] = b1.y; Bs[lk + 2][lr + 32] = b1.z; Bs[lk + 3][lr + 32] = b1.w;
    __syncthreads();

#pragma unroll
    for (int k = 0; k < 32; ++k) {
      float a[4], b[4];
#pragma unroll
      for (int q = 0; q < 4; ++q) { a[q] = As[k][tm + q]; b[q] = Bs[k][tn + q]; }
#pragma unroll
      for (int ii = 0; ii < 4; ++ii)
#pragma unroll
        for (int jj = 0; jj < 4; ++jj)
          acc[ii][jj] = fmaf(a[ii], b[jj], acc[ii][jj]);
    }
  }

  const float4 bv = *reinterpret_cast<const float4*>(&bias[bn + tn]);
#pragma unroll
  for (int ii = 0; ii < 4; ++ii) {
    float4 o;
    o.x = acc[ii][0] + bv.x;
    o.y = acc[ii][1] + bv.y;
    o.z = acc[ii][2] + bv.z;
    o.w = acc[ii][3] + bv.w;
    *reinterpret_cast<float4*>(&outp[(size_t)(bm + tm + ii) * ND + bn + tn]) = o;
  }
}

extern "C" void kernel_launch(void* const* d_in, const int* in_sizes, int n_in,
                              void* d_out, int out_size, void* d_ws, size_t ws_size,
                              hipStream_t stream) {
  (void)in_sizes; (void)n_in; (void)out_size; (void)ws_size;
  const float* features  = (const float*)d_in[0];
  const float* keypoints = (const float*)d_in[1];
  const float* conv_w    = (const float*)d_in[2];
  const float* conv_b    = (const float*)d_in[3];
  float* outp   = (float*)d_out;
  float* pooled = (float*)d_ws;   // 1600*768*4 = 4.9 MB scratch

  pool_kernel<<<NKP, 256, 0, stream>>>(features, keypoints, pooled);

  dim3 grid(NKP / 64, ND / 64);   // 25 x 12
  gemm_kernel<<<grid, 256, 0, stream>>>(pooled, conv_w, conv_b, outp);
}

// Round 2
// 62.302 us; speedup vs baseline: 1.5788x; 1.5788x over previous
//
#include <hip/hip_runtime.h>

// Problem constants (match reference)
#define NB 8
#define NT 8
#define NO 25
#define NC 3
#define NH 192
#define NW 640
#define NP 16
#define ND 768
#define NGH 12
#define NGW 2
#define NKP (NB*NT*NO)   // 1600 keypoints
#define NK (NC*NP*NP)    // 768 (GEMM K)

#define S_STRIDE 38      // footprint LDS row stride in floats (nq<=10 -> 40 cols max loaded, stride 38 ok? see note)

// NOTE on S_STRIDE: we stage nq<=10 float4 groups = up to 40 floats, BUT only
// columns [0, cmax-cmin_al] <= 36 are ever read. Writes use 2x float2 so a
// stride of 38 would clip the last group's tail. Use 40 to be safe:
#undef S_STRIDE
#define S_STRIDE 40

typedef __attribute__((ext_vector_type(4))) float  f32x4;
typedef __attribute__((ext_vector_type(8))) short  bf16x8;

static __device__ __forceinline__ unsigned short f2bf(float f) {
  union { float f; unsigned u; } x; x.f = f;
  unsigned r = x.u + 0x7FFFu + ((x.u >> 16) & 1u);   // round-to-nearest-even
  return (unsigned short)(r >> 16);
}

// ---------------------------------------------------------------------------
// Kernel 0: conv_w f32 -> bf16  (589824 elements = 147456 float4)
// ---------------------------------------------------------------------------
__global__ __launch_bounds__(256) void convw_kernel(
    const float* __restrict__ w, unsigned short* __restrict__ wb) {
  const int i = blockIdx.x * 256 + threadIdx.x;   // float4 index
  const float4 v = reinterpret_cast<const float4*>(w)[i];
  ushort4 o;
  o.x = f2bf(v.x); o.y = f2bf(v.y); o.z = f2bf(v.z); o.w = f2bf(v.w);
  reinterpret_cast<ushort4*>(wb)[i] = o;
}

// ---------------------------------------------------------------------------
// Kernel 1: ROI-align pooling. One block (256 threads) per keypoint.
// Validity is block-uniform: y-valid iff gy<gh, x-valid iff gx<gw (proof:
// kx>=192 => by2=192 always; all sample coords lie in (-0.5, size-0.5)).
// Stages the footprint per-channel in LDS with float4 loads (no division),
// then bilinear-samples from LDS. Output written as bf16, k = c*256+i*16+j.
// ---------------------------------------------------------------------------
__global__ __launch_bounds__(256) void pool_kernel(
    const float* __restrict__ features,   // [B][C][T][H][W] f32
    const float* __restrict__ keypoints,  // [N][3] (kx, ky, kr)
    unsigned short* __restrict__ pooled)  // [N][768] bf16
{
  __shared__ float S[NH * S_STRIDE];      // 192*40*4 = 30720 B
  __shared__ float s_ly[NP * NGH];
  __shared__ int   s_y0[NP * NGH];
  __shared__ float s_lx[NP * NGW];
  __shared__ int   s_x0[NP * NGW];

  // XCD-chunked swizzle: 1600 = 8 * 200; XCD x gets keypoints [x*200, x*200+200)
  const int n   = (blockIdx.x & 7) * (NKP / 8) + (blockIdx.x >> 3);
  const int tid = threadIdx.x;

  const float kx = keypoints[n * 3 + 0];
  const float ky = keypoints[n * 3 + 1];
  const float kr = keypoints[n * 3 + 2];

  // Boxes exactly as reference (by2 uses kx — reference quirk, keep it)
  const float bx1 = fmaxf(kx - kr, 0.0f);
  const float by1 = fmaxf(ky - kr, 0.0f);
  const float bx2 = fminf(kx + kr, (float)NW);
  const float by2 = fminf(kx + kr, (float)NH);

  const float start_h = by1 - 0.5f;
  const float start_w = bx1 - 0.5f;
  const float bin_h = (by2 - by1) * (1.0f / (float)NP);
  const float bin_w = (bx2 - bx1) * (1.0f / (float)NP);
  const int gh = (int)ceilf(bin_h);       // == ceil(roi_h / P), 1..12
  const int gw = (int)ceilf(bin_w);       // 1..2
  const float ghf = (float)max(gh, 1);
  const float gwf = (float)max(gw, 1);
  const float inv_count = 1.0f / (float)max(gh * gw, 1);

  // --- per-bin sample tables ---
  if (tid < NP * NGH) {
    const int i = tid / NGH, g = tid % NGH;
    const float c = start_h + (float)i * bin_h + ((float)g + 0.5f) * (bin_h / ghf);
    const float cc = fminf(fmaxf(c, 0.0f), (float)(NH - 1));
    const int lo = (int)floorf(cc);
    s_ly[tid] = cc - (float)lo;
    s_y0[tid] = lo;
  } else if (tid < NP * NGH + NP * NGW) {
    const int t2 = tid - NP * NGH;
    const int j = t2 >> 1, g = t2 & 1;
    const float c = start_w + (float)j * bin_w + ((float)g + 0.5f) * (bin_w / gwf);
    const float cc = fminf(fmaxf(c, 0.0f), (float)(NW - 1));
    const int lo = (int)floorf(cc);
    s_lx[t2] = cc - (float)lo;
    s_x0[t2] = lo;
  }

  // --- footprint extent (block-uniform; samples monotonic in bin,g) ---
  const float cy_min = start_h + 0.5f * (bin_h / ghf);
  const float cy_max = start_h + 15.0f * bin_h + ((float)(gh - 1) + 0.5f) * (bin_h / ghf);
  const float cx_min = start_w + 0.5f * (bin_w / gwf);
  const float cx_max = start_w + 15.0f * bin_w + ((float)(gw - 1) + 0.5f) * (bin_w / gwf);
  const int rmin = (int)floorf(fminf(fmaxf(cy_min, 0.0f), (float)(NH - 1)));
  const int rmax = min((int)floorf(fminf(fmaxf(cy_max, 0.0f), (float)(NH - 1))) + 1, NH - 1);
  const int cmin = (int)floorf(fminf(fmaxf(cx_min, 0.0f), (float)(NW - 1)));
  const int cmax = min((int)floorf(fminf(fmaxf(cx_max, 0.0f), (float)(NW - 1))) + 1, NW - 1);
  const int nrows = rmax - rmin + 1;          // <= 192
  const int cmin_al = cmin & ~3;              // 4-aligned for float4 loads
  const int nq = ((cmax - cmin_al) >> 2) + 1; // float4 groups per row, <= 10

  const int img  = n / NO;                    // b*T + t
  const int bb   = img / NT;
  const int timg = img % NT;

  const int i = tid >> 4;
  const int j = tid & 15;

  __syncthreads();

  // Hoist this thread's table entries into registers (constant across channels)
  int   ry0a[NGH], ry1a[NGH];
  float lya[NGH];
#pragma unroll
  for (int gy = 0; gy < NGH; ++gy) {
    const int y0 = s_y0[i * NGH + gy];
    lya[gy]  = s_ly[i * NGH + gy];
    ry0a[gy] = y0 - rmin;
    ry1a[gy] = min(y0 + 1, NH - 1) - rmin;
  }
  int   cx0a[NGW], cx1a[NGW];
  float lxa[NGW];
#pragma unroll
  for (int gx = 0; gx < NGW; ++gx) {
    const int x0 = s_x0[j * NGW + gx];
    lxa[gx]  = s_lx[j * NGW + gx];
    cx0a[gx] = x0 - cmin_al;
    cx1a[gx] = min(x0 + 1, NW - 1) - cmin_al;
  }

  const int rr = tid >> 4;   // staging: 16 rows per iteration
  const int cc = tid & 15;   // float4 group within row (cc < nq active)

  for (int ch = 0; ch < NC; ++ch) {
    __syncthreads();  // protect S against overwrite while prior reads in flight
    const float* __restrict__ src =
        features + (size_t)((bb * NC + ch) * NT + timg) * (NH * NW);
    for (int r = rr; r < nrows; r += 16) {
      if (cc < nq) {
        const int gc = cmin_al + (cc << 2);
        const float* p = src + (size_t)(rmin + r) * NW + gc;
        float4 v;
        if (gc + 3 < NW) {
          v = *reinterpret_cast<const float4*>(p);
        } else {                       // only possible at the image's right edge
          v.x = p[0];
          v.y = p[min(1, NW - 1 - gc)];
          v.z = p[min(2, NW - 1 - gc)];
          v.w = p[min(3, NW - 1 - gc)];
        }
        float* srow = &S[r * S_STRIDE + (cc << 2)];
        *reinterpret_cast<float2*>(srow)     = make_float2(v.x, v.y);
        *reinterpret_cast<float2*>(srow + 2) = make_float2(v.z, v.w);
      }
    }
    __syncthreads();

    float acc = 0.0f;
#pragma unroll
    for (int gy = 0; gy < NGH; ++gy) {
      if (gy >= gh) break;             // block-uniform bound
      const int ry0 = ry0a[gy] * S_STRIDE;
      const int ry1 = ry1a[gy] * S_STRIDE;
      const float ly = lya[gy];
      const float hy = 1.0f - ly;
#pragma unroll
      for (int gx = 0; gx < NGW; ++gx) {
        if (gx >= gw) break;           // block-uniform bound
        const int cx0 = cx0a[gx];
        const int cx1 = cx1a[gx];
        const float lx = lxa[gx];
        const float hx = 1.0f - lx;
        const float v00 = S[ry0 + cx0];
        const float v01 = S[ry0 + cx1];
        const float v10 = S[ry1 + cx0];
        const float v11 = S[ry1 + cx1];
        acc += hy * (hx * v00 + lx * v01) + ly * (hx * v10 + lx * v11);
      }
    }
    pooled[(size_t)n * NK + ch * (NP * NP) + tid] = f2bf(acc * inv_count);
  }
}

// ---------------------------------------------------------------------------
// Kernel 2: bf16 MFMA GEMM  out[1600][768] = A[1600][768] . Bw[768][768]^T + b
// BM=64, BN=128, BK=32, 256 threads = 4 waves (2x2), wave tile 32x64.
// A and Bw both K-major bf16; staged via global_load_lds (16B, linear LDS).
// v_mfma_f32_16x16x32_bf16; fp32 accumulate + fp32 out.
// ---------------------------------------------------------------------------
#define BM 64
#define BN 128
#define BK 32

static __device__ __forceinline__ void gld_lds16(const unsigned short* g,
                                                 unsigned short* l) {
  __builtin_amdgcn_global_load_lds(
      (const __attribute__((address_space(1))) unsigned int*)g,
      (__attribute__((address_space(3))) unsigned int*)l,
      16, 0, 0);
}

__global__ __launch_bounds__(256) void gemm_kernel(
    const unsigned short* __restrict__ A,    // [1600][768] bf16 (pooled)
    const unsigned short* __restrict__ Bw,   // [768][768]  bf16 (conv_w)
    const float* __restrict__ bias,          // [768]
    float* __restrict__ outp)                // [1600][768] f32
{
  __shared__ __align__(16) unsigned short As[BM * BK];   // 4 KB
  __shared__ __align__(16) unsigned short Bs[BN * BK];   // 8 KB

  const int tid = threadIdx.x;
  const int w = tid >> 6;           // wave 0..3
  const int l = tid & 63;           // lane
  const int bm = blockIdx.x * BM;
  const int bn = blockIdx.y * BN;

  // staging: thread (w,l) -> tile row w*16 + l/4, k offset (l%4)*8
  const int arow = (w << 4) + (l >> 2);
  const int kofs = (l & 3) << 3;

  // compute: wave (wr,wc) owns 32x64; lane: fragment row/col l&15, k-half l>>4
  const int wr = w >> 1, wc = w & 1;
  const int lr = l & 15;
  const int lk = (l >> 4) << 3;

  f32x4 acc[2][4] = {};

  for (int k0 = 0; k0 < NK; k0 += BK) {
    if (k0) __syncthreads();          // protect LDS from overwrite
    gld_lds16(A  + (size_t)(bm + arow) * NK + k0 + kofs, As + (w << 9));
    gld_lds16(Bw + (size_t)(bn + arow) * NK + k0 + kofs, Bs + (w << 9));
    gld_lds16(Bw + (size_t)(bn + 64 + arow) * NK + k0 + kofs, Bs + 2048 + (w << 9));
    __syncthreads();                  // drains vmcnt before LDS reads

    const unsigned short* pa = As + ((wr << 5) + lr) * BK + lk;
    const bf16x8 a0 = *reinterpret_cast<const bf16x8*>(pa);
    const bf16x8 a1 = *reinterpret_cast<const bf16x8*>(pa + 16 * BK);
    const unsigned short* pb = Bs + ((wc << 6) + lr) * BK + lk;
#pragma unroll
    for (int ni = 0; ni < 4; ++ni) {
      const bf16x8 b = *reinterpret_cast<const bf16x8*>(pb + ni * 16 * BK);
      acc[0][ni] = __builtin_amdgcn_mfma_f32_16x16x32_bf16(a0, b, acc[0][ni], 0, 0, 0);
      acc[1][ni] = __builtin_amdgcn_mfma_f32_16x16x32_bf16(a1, b, acc[1][ni], 0, 0, 0);
    }
  }

  // Epilogue: C/D layout col = lane&15, row = (lane>>4)*4 + reg
#pragma unroll
  for (int ni = 0; ni < 4; ++ni) {
    const int col = bn + (wc << 6) + (ni << 4) + lr;
    const float bv = bias[col];
#pragma unroll
    for (int mi = 0; mi < 2; ++mi) {
      const int rbase = bm + (wr << 5) + (mi << 4) + ((l >> 4) << 2);
#pragma unroll
      for (int q = 0; q < 4; ++q) {
        outp[(size_t)(rbase + q) * ND + col] = acc[mi][ni][q] + bv;
      }
    }
  }
}

extern "C" void kernel_launch(void* const* d_in, const int* in_sizes, int n_in,
                              void* d_out, int out_size, void* d_ws, size_t ws_size,
                              hipStream_t stream) {
  (void)in_sizes; (void)n_in; (void)out_size; (void)ws_size;
  const float* features  = (const float*)d_in[0];
  const float* keypoints = (const float*)d_in[1];
  const float* conv_w    = (const float*)d_in[2];
  const float* conv_b    = (const float*)d_in[3];
  float* outp = (float*)d_out;

  unsigned short* pooled = (unsigned short*)d_ws;                   // 2,457,600 B
  unsigned short* wbf    = (unsigned short*)((char*)d_ws + 2457600); // 1,179,648 B

  convw_kernel<<<(NK * ND) / (256 * 4), 256, 0, stream>>>(conv_w, wbf);
  pool_kernel<<<NKP, 256, 0, stream>>>(features, keypoints, pooled);

  dim3 grid(NKP / BM, ND / BN);   // 25 x 6
  gemm_kernel<<<grid, 256, 0, stream>>>(pooled, wbf, conv_b, outp);
}

// Round 3
// 45.594 us; speedup vs baseline: 2.1574x; 1.3664x over previous
//
#include <hip/hip_runtime.h>

// Problem constants (match reference)
#define NB 8
#define NT 8
#define NO 25
#define NC 3
#define NH 192
#define NW 640
#define NP 16
#define ND 768
#define NGH 12
#define NGW 2
#define NKP (NB*NT*NO)   // 1600 keypoints
#define NK (NC*NP*NP)    // 768 (GEMM K)
#define NTASK (NKP*NC)   // 4800 pool blocks

#define S_STRIDE 41      // odd stride: breaks even-bank stripes on sampling reads

typedef __attribute__((ext_vector_type(4))) float  f32x4;
typedef __attribute__((ext_vector_type(8))) short  bf16x8;

static __device__ __forceinline__ unsigned short f2bf(float f) {
  union { float f; unsigned u; } x; x.f = f;
  unsigned r = x.u + 0x7FFFu + ((x.u >> 16) & 1u);   // round-to-nearest-even
  return (unsigned short)(r >> 16);
}

// ---------------------------------------------------------------------------
// Kernel 0: conv_w f32 -> bf16  (589824 elements = 147456 float4)
// ---------------------------------------------------------------------------
__global__ __launch_bounds__(256) void convw_kernel(
    const float* __restrict__ w, unsigned short* __restrict__ wb) {
  const int i = blockIdx.x * 256 + threadIdx.x;   // float4 index
  const float4 v = reinterpret_cast<const float4*>(w)[i];
  ushort4 o;
  o.x = f2bf(v.x); o.y = f2bf(v.y); o.z = f2bf(v.z); o.w = f2bf(v.w);
  reinterpret_cast<ushort4*>(wb)[i] = o;
}

// ---------------------------------------------------------------------------
// Kernel 1: ROI-align pooling. One block (256 threads) per (keypoint,channel).
// Single phase: register-stage the footprint (<=8 predicated float4 loads,
// all in flight together), write LDS, one barrier, then bilinear-sample.
// Validity is block-uniform (gy<gh, gx<gw) — coords always in (-0.5,size-0.5).
// pooled layout: [n][k], k = c*256 + i*16 + j (matches conv_w flat K).
// ---------------------------------------------------------------------------
__global__ __launch_bounds__(256) void pool_kernel(
    const float* __restrict__ features,   // [B][C][T][H][W] f32
    const float* __restrict__ keypoints,  // [N][3] (kx, ky, kr)
    unsigned short* __restrict__ pooled)  // [N][768] bf16
{
  __shared__ float S[NH * S_STRIDE];      // 192*41*4 = 31488 B

  // XCD-chunked swizzle over 4800 tasks (4800 = 8 * 600)
  const int bid = blockIdx.x;
  const int t   = (bid & 7) * (NTASK / 8) + (bid >> 3);
  const int n   = t / 3;
  const int ch  = t - 3 * n;
  const int tid = threadIdx.x;

  const float kx = keypoints[n * 3 + 0];
  const float ky = keypoints[n * 3 + 1];
  const float kr = keypoints[n * 3 + 2];

  // Boxes exactly as reference (by2 uses kx — reference quirk, keep it)
  const float bx1 = fmaxf(kx - kr, 0.0f);
  const float by1 = fmaxf(ky - kr, 0.0f);
  const float bx2 = fminf(kx + kr, (float)NW);
  const float by2 = fminf(kx + kr, (float)NH);

  const float start_h = by1 - 0.5f;
  const float start_w = bx1 - 0.5f;
  const float bin_h = (by2 - by1) * (1.0f / (float)NP);
  const float bin_w = (bx2 - bx1) * (1.0f / (float)NP);
  const int gh = (int)ceilf(bin_h);       // == ceil(roi_h / P), 1..12
  const int gw = (int)ceilf(bin_w);       // 1..2
  const float ghf = (float)max(gh, 1);
  const float gwf = (float)max(gw, 1);
  const float inv_count = 1.0f / (float)max(gh * gw, 1);
  const float sub_h = bin_h / ghf;        // sub-sample spacing
  const float sub_w = bin_w / gwf;

  // --- footprint extent (block-uniform; samples monotonic in bin,g) ---
  const float cy_min = start_h + 0.5f * sub_h;
  const float cy_max = start_h + 15.0f * bin_h + ((float)(gh - 1) + 0.5f) * sub_h;
  const float cx_min = start_w + 0.5f * sub_w;
  const float cx_max = start_w + 15.0f * bin_w + ((float)(gw - 1) + 0.5f) * sub_w;
  const int rmin = (int)floorf(fminf(fmaxf(cy_min, 0.0f), (float)(NH - 1)));
  const int rmax = min((int)floorf(fminf(fmaxf(cy_max, 0.0f), (float)(NH - 1))) + 1, NH - 1);
  const int cmin = (int)floorf(fminf(fmaxf(cx_min, 0.0f), (float)(NW - 1)));
  const int cmax = min((int)floorf(fminf(fmaxf(cx_max, 0.0f), (float)(NW - 1))) + 1, NW - 1);
  const int nrows = rmax - rmin + 1;          // <= 192
  const int cmin_al = cmin & ~3;              // 4-aligned for float4 loads
  const int nq = ((cmax - cmin_al) >> 2) + 1; // float4 groups per row, <= 10
  const int tot = nrows * nq;                 // <= 1920
  const float inv_nq = 1.0f / (float)nq;

  const int img  = n / NO;                    // b*T + t
  const int bb   = img / NT;
  const int timg = img % NT;
  const float* __restrict__ src =
      features + (size_t)((bb * NC + ch) * NT + timg) * (NH * NW);

  // --- register staging: up to 8 predicated float4 loads, all independent ---
  float4 v0, v1, v2, v3, v4, v5, v6, v7;
  int ro0, ro1, ro2, ro3, ro4, ro5, ro6, ro7;   // LDS float offset, -1 = skip

#define STAGE_LOAD(Q, V, RO)                                                 \
  {                                                                          \
    const int e = tid + (Q << 8);                                            \
    if (e < tot) {                                                           \
      const int r  = (int)(((float)e + 0.5f) * inv_nq);                      \
      const int c4 = (e - r * nq) << 2;                                      \
      const int gc = cmin_al + c4;                                           \
      const float* p = src + (size_t)(rmin + r) * NW + gc;                   \
      if (gc + 3 < NW) { V = *reinterpret_cast<const float4*>(p); }          \
      else { V.x = p[0]; V.y = p[min(1, NW - 1 - gc)];                       \
             V.z = p[min(2, NW - 1 - gc)]; V.w = p[min(3, NW - 1 - gc)]; }   \
      RO = r * S_STRIDE + c4;                                                \
    } else { RO = -1; }                                                      \
  }

  STAGE_LOAD(0, v0, ro0) STAGE_LOAD(1, v1, ro1) STAGE_LOAD(2, v2, ro2)
  STAGE_LOAD(3, v3, ro3) STAGE_LOAD(4, v4, ro4) STAGE_LOAD(5, v5, ro5)
  STAGE_LOAD(6, v6, ro6) STAGE_LOAD(7, v7, ro7)
#undef STAGE_LOAD

#define STAGE_WRITE(V, RO)                                                   \
  if (RO >= 0) { float* s = &S[RO];                                          \
    s[0] = V.x; s[1] = V.y; s[2] = V.z; s[3] = V.w; }

  STAGE_WRITE(v0, ro0) STAGE_WRITE(v1, ro1) STAGE_WRITE(v2, ro2)
  STAGE_WRITE(v3, ro3) STAGE_WRITE(v4, ro4) STAGE_WRITE(v5, ro5)
  STAGE_WRITE(v6, ro6) STAGE_WRITE(v7, ro7)
#undef STAGE_WRITE

  __syncthreads();

  // --- bilinear sampling (per-thread coords; reference formula order) ---
  const int i = tid >> 4;
  const int j = tid & 15;

  float lxa[NGW]; int cx0a[NGW], cx1a[NGW];
#pragma unroll
  for (int gx = 0; gx < NGW; ++gx) {
    const float c = start_w + (float)j * bin_w + ((float)gx + 0.5f) * sub_w;
    const float cc = fminf(fmaxf(c, 0.0f), (float)(NW - 1));
    const int x0 = (int)floorf(cc);
    lxa[gx]  = cc - (float)x0;
    cx0a[gx] = x0 - cmin_al;
    cx1a[gx] = min(x0 + 1, NW - 1) - cmin_al;
  }

  float acc = 0.0f;
#pragma unroll
  for (int gy = 0; gy < NGH; ++gy) {
    if (gy >= gh) break;               // block-uniform bound
    const float c = start_h + (float)i * bin_h + ((float)gy + 0.5f) * sub_h;
    const float cc = fminf(fmaxf(c, 0.0f), (float)(NH - 1));
    const int y0 = (int)floorf(cc);
    const float ly = cc - (float)y0;
    const float hy = 1.0f - ly;
    const int ry0 = (y0 - rmin) * S_STRIDE;
    const int ry1 = (min(y0 + 1, NH - 1) - rmin) * S_STRIDE;
#pragma unroll
    for (int gx = 0; gx < NGW; ++gx) {
      if (gx >= gw) break;             // block-uniform bound
      const float lx = lxa[gx];
      const float hx = 1.0f - lx;
      const float v00 = S[ry0 + cx0a[gx]];
      const float v01 = S[ry0 + cx1a[gx]];
      const float v10 = S[ry1 + cx0a[gx]];
      const float v11 = S[ry1 + cx1a[gx]];
      acc += hy * (hx * v00 + lx * v01) + ly * (hx * v10 + lx * v11);
    }
  }
  pooled[(size_t)n * NK + ch * (NP * NP) + tid] = f2bf(acc * inv_count);
}

// ---------------------------------------------------------------------------
// Kernel 2: bf16 MFMA GEMM  out[1600][768] = A[1600][768] . Bw[768][768]^T + b
// BM=64, BN=128, BK=32, 256 threads = 4 waves (2x2), wave tile 32x64.
// ---------------------------------------------------------------------------
#define BM 64
#define BN 128
#define BK 32

static __device__ __forceinline__ void gld_lds16(const unsigned short* g,
                                                 unsigned short* l) {
  __builtin_amdgcn_global_load_lds(
      (const __attribute__((address_space(1))) unsigned int*)g,
      (__attribute__((address_space(3))) unsigned int*)l,
      16, 0, 0);
}

__global__ __launch_bounds__(256) void gemm_kernel(
    const unsigned short* __restrict__ A,    // [1600][768] bf16 (pooled)
    const unsigned short* __restrict__ Bw,   // [768][768]  bf16 (conv_w)
    const float* __restrict__ bias,          // [768]
    float* __restrict__ outp)                // [1600][768] f32
{
  __shared__ __align__(16) unsigned short As[BM * BK];   // 4 KB
  __shared__ __align__(16) unsigned short Bs[BN * BK];   // 8 KB

  const int tid = threadIdx.x;
  const int w = tid >> 6;           // wave 0..3
  const int l = tid & 63;           // lane
  const int bm = blockIdx.x * BM;
  const int bn = blockIdx.y * BN;

  // staging: thread (w,l) -> tile row w*16 + l/4, k offset (l%4)*8
  const int arow = (w << 4) + (l >> 2);
  const int kofs = (l & 3) << 3;

  // compute: wave (wr,wc) owns 32x64; lane: fragment row/col l&15, k-half l>>4
  const int wr = w >> 1, wc = w & 1;
  const int lr = l & 15;
  const int lk = (l >> 4) << 3;

  f32x4 acc[2][4] = {};

  for (int k0 = 0; k0 < NK; k0 += BK) {
    if (k0) __syncthreads();          // protect LDS from overwrite
    gld_lds16(A  + (size_t)(bm + arow) * NK + k0 + kofs, As + (w << 9));
    gld_lds16(Bw + (size_t)(bn + arow) * NK + k0 + kofs, Bs + (w << 9));
    gld_lds16(Bw + (size_t)(bn + 64 + arow) * NK + k0 + kofs, Bs + 2048 + (w << 9));
    __syncthreads();                  // drains vmcnt before LDS reads

    const unsigned short* pa = As + ((wr << 5) + lr) * BK + lk;
    const bf16x8 a0 = *reinterpret_cast<const bf16x8*>(pa);
    const bf16x8 a1 = *reinterpret_cast<const bf16x8*>(pa + 16 * BK);
    const unsigned short* pb = Bs + ((wc << 6) + lr) * BK + lk;
#pragma unroll
    for (int ni = 0; ni < 4; ++ni) {
      const bf16x8 b = *reinterpret_cast<const bf16x8*>(pb + ni * 16 * BK);
      acc[0][ni] = __builtin_amdgcn_mfma_f32_16x16x32_bf16(a0, b, acc[0][ni], 0, 0, 0);
      acc[1][ni] = __builtin_amdgcn_mfma_f32_16x16x32_bf16(a1, b, acc[1][ni], 0, 0, 0);
    }
  }

  // Epilogue: C/D layout col = lane&15, row = (lane>>4)*4 + reg
#pragma unroll
  for (int ni = 0; ni < 4; ++ni) {
    const int col = bn + (wc << 6) + (ni << 4) + lr;
    const float bv = bias[col];
#pragma unroll
    for (int mi = 0; mi < 2; ++mi) {
      const int rbase = bm + (wr << 5) + (mi << 4) + ((l >> 4) << 2);
#pragma unroll
      for (int q = 0; q < 4; ++q) {
        outp[(size_t)(rbase + q) * ND + col] = acc[mi][ni][q] + bv;
      }
    }
  }
}

extern "C" void kernel_launch(void* const* d_in, const int* in_sizes, int n_in,
                              void* d_out, int out_size, void* d_ws, size_t ws_size,
                              hipStream_t stream) {
  (void)in_sizes; (void)n_in; (void)out_size; (void)ws_size;
  const float* features  = (const float*)d_in[0];
  const float* keypoints = (const float*)d_in[1];
  const float* conv_w    = (const float*)d_in[2];
  const float* conv_b    = (const float*)d_in[3];
  float* outp = (float*)d_out;

  unsigned short* pooled = (unsigned short*)d_ws;                    // 2,457,600 B
  unsigned short* wbf    = (unsigned short*)((char*)d_ws + 2457600); // 1,179,648 B

  convw_kernel<<<(NK * ND) / (256 * 4), 256, 0, stream>>>(conv_w, wbf);
  pool_kernel<<<NTASK, 256, 0, stream>>>(features, keypoints, pooled);

  dim3 grid(NKP / BM, ND / BN);   // 25 x 6
  gemm_kernel<<<grid, 256, 0, stream>>>(pooled, wbf, conv_b, outp);
}

// Round 4
// 38.478 us; speedup vs baseline: 2.5563x; 1.1849x over previous
//
#include <hip/hip_runtime.h>

// Problem constants (match reference)
#define NB 8
#define NT 8
#define NO 25
#define NC 3
#define NH 192
#define NW 640
#define NP 16
#define ND 768
#define NGH 12
#define NGW 2
#define NKP (NB*NT*NO)   // 1600 keypoints
#define NK (NC*NP*NP)    // 768 (GEMM K)
#define NTASK (NKP*NC)   // 4800 pool blocks
#define NCVW ((NK*ND)/(256*4))  // 576 convw blocks (float4 per thread)

#define S_STRIDE 41      // odd stride: breaks even-bank stripes on sampling reads

typedef __attribute__((ext_vector_type(4))) float  f32x4;
typedef __attribute__((ext_vector_type(8))) short  bf16x8;

static __device__ __forceinline__ unsigned short f2bf(float f) {
  union { float f; unsigned u; } x; x.f = f;
  unsigned r = x.u + 0x7FFFu + ((x.u >> 16) & 1u);   // round-to-nearest-even
  return (unsigned short)(r >> 16);
}

// ---------------------------------------------------------------------------
// Kernel 1 (fused): blocks [0,NCVW) convert conv_w f32->bf16;
// blocks [NCVW, NCVW+NTASK) do ROI-align pooling, one per (keypoint,channel).
// ---------------------------------------------------------------------------
__global__ __launch_bounds__(256) void pool_convw_kernel(
    const float* __restrict__ features,   // [B][C][T][H][W] f32
    const float* __restrict__ keypoints,  // [N][3] (kx, ky, kr)
    const float* __restrict__ conv_w,     // [768][768] f32
    unsigned short* __restrict__ pooled,  // [N][768] bf16
    unsigned short* __restrict__ wbf)     // [768][768] bf16
{
  __shared__ float S[NH * S_STRIDE];      // 192*41*4 = 31488 B

  const int bid = blockIdx.x;
  const int tid = threadIdx.x;

  if (bid < NCVW) {                       // ---- conv_w convert path ----
    const int i = bid * 256 + tid;        // float4 index
    const float4 v = reinterpret_cast<const float4*>(conv_w)[i];
    ushort4 o;
    o.x = f2bf(v.x); o.y = f2bf(v.y); o.z = f2bf(v.z); o.w = f2bf(v.w);
    reinterpret_cast<ushort4*>(wbf)[i] = o;
    return;                               // no barrier on this path (block-uniform)
  }

  // ---- pooling path ----
  // XCD-chunked swizzle over 4800 tasks (4800 = 8*600; NCVW = 576 = 72*8
  // keeps the blockIdx->XCD phase aligned)
  const int rb = bid - NCVW;
  const int t  = (rb & 7) * (NTASK / 8) + (rb >> 3);
  const int n  = t / 3;
  const int ch = t - 3 * n;

  const float kx = keypoints[n * 3 + 0];
  const float ky = keypoints[n * 3 + 1];
  const float kr = keypoints[n * 3 + 2];

  // Boxes exactly as reference (by2 uses kx — reference quirk, keep it)
  const float bx1 = fmaxf(kx - kr, 0.0f);
  const float by1 = fmaxf(ky - kr, 0.0f);
  const float bx2 = fminf(kx + kr, (float)NW);
  const float by2 = fminf(kx + kr, (float)NH);

  const float start_h = by1 - 0.5f;
  const float start_w = bx1 - 0.5f;
  const float bin_h = (by2 - by1) * (1.0f / (float)NP);
  const float bin_w = (bx2 - bx1) * (1.0f / (float)NP);
  const int gh = (int)ceilf(bin_h);       // == ceil(roi_h / P), 1..12
  const int gw = (int)ceilf(bin_w);       // 1..2
  const float ghf = (float)max(gh, 1);
  const float gwf = (float)max(gw, 1);
  const float inv_count = 1.0f / (float)max(gh * gw, 1);
  const float sub_h = bin_h / ghf;        // sub-sample spacing
  const float sub_w = bin_w / gwf;

  // --- footprint extent (block-uniform; samples monotonic in bin,g) ---
  const float cy_min = start_h + 0.5f * sub_h;
  const float cy_max = start_h + 15.0f * bin_h + ((float)(gh - 1) + 0.5f) * sub_h;
  const float cx_min = start_w + 0.5f * sub_w;
  const float cx_max = start_w + 15.0f * bin_w + ((float)(gw - 1) + 0.5f) * sub_w;
  const int rmin = (int)floorf(fminf(fmaxf(cy_min, 0.0f), (float)(NH - 1)));
  const int rmax = min((int)floorf(fminf(fmaxf(cy_max, 0.0f), (float)(NH - 1))) + 1, NH - 1);
  const int cmin = (int)floorf(fminf(fmaxf(cx_min, 0.0f), (float)(NW - 1)));
  const int cmax = min((int)floorf(fminf(fmaxf(cx_max, 0.0f), (float)(NW - 1))) + 1, NW - 1);
  const int nrows = rmax - rmin + 1;          // <= 192
  const int cmin_al = cmin & ~3;              // 4-aligned for float4 loads
  const int nq = ((cmax - cmin_al) >> 2) + 1; // float4 groups per row, <= 10
  const int tot = nrows * nq;                 // <= 1920
  const float inv_nq = 1.0f / (float)nq;

  const int img  = n / NO;                    // b*T + t
  const int bb   = img / NT;
  const int timg = img % NT;
  const float* __restrict__ src =
      features + (size_t)((bb * NC + ch) * NT + timg) * (NH * NW);

  // --- register staging: up to 8 predicated float4 loads, all independent ---
  float4 v0, v1, v2, v3, v4, v5, v6, v7;
  int ro0, ro1, ro2, ro3, ro4, ro5, ro6, ro7;   // LDS float offset, -1 = skip

#define STAGE_LOAD(Q, V, RO)                                                 \
  {                                                                          \
    const int e = tid + (Q << 8);                                            \
    if (e < tot) {                                                           \
      const int r  = (int)(((float)e + 0.5f) * inv_nq);                      \
      const int c4 = (e - r * nq) << 2;                                      \
      const int gc = cmin_al + c4;                                           \
      const float* p = src + (size_t)(rmin + r) * NW + gc;                   \
      if (gc + 3 < NW) { V = *reinterpret_cast<const float4*>(p); }          \
      else { V.x = p[0]; V.y = p[min(1, NW - 1 - gc)];                       \
             V.z = p[min(2, NW - 1 - gc)]; V.w = p[min(3, NW - 1 - gc)]; }   \
      RO = r * S_STRIDE + c4;                                                \
    } else { RO = -1; }                                                      \
  }

  STAGE_LOAD(0, v0, ro0) STAGE_LOAD(1, v1, ro1) STAGE_LOAD(2, v2, ro2)
  STAGE_LOAD(3, v3, ro3) STAGE_LOAD(4, v4, ro4) STAGE_LOAD(5, v5, ro5)
  STAGE_LOAD(6, v6, ro6) STAGE_LOAD(7, v7, ro7)
#undef STAGE_LOAD

#define STAGE_WRITE(V, RO)                                                   \
  if (RO >= 0) { float* s = &S[RO];                                          \
    s[0] = V.x; s[1] = V.y; s[2] = V.z; s[3] = V.w; }

  STAGE_WRITE(v0, ro0) STAGE_WRITE(v1, ro1) STAGE_WRITE(v2, ro2)
  STAGE_WRITE(v3, ro3) STAGE_WRITE(v4, ro4) STAGE_WRITE(v5, ro5)
  STAGE_WRITE(v6, ro6) STAGE_WRITE(v7, ro7)
#undef STAGE_WRITE

  // zero pad column (first column beyond staged region): the x0+1 read hits
  // it only when lx==0 (weight 0) — keep it finite, not stale-LDS NaN bits.
  const int padc = nq << 2;                   // <= 40 < S_STRIDE
  if (tid < nrows) S[tid * S_STRIDE + padc] = 0.0f;

  __syncthreads();

  // --- bilinear sampling (per-thread coords; reference formula order) ---
  const int i = tid >> 4;
  const int j = tid & 15;

  float lxv[NGW]; int cxv[NGW];
#pragma unroll
  for (int gx = 0; gx < NGW; ++gx) {
    const float c = start_w + (float)j * bin_w + ((float)gx + 0.5f) * sub_w;
    const float cc = fminf(fmaxf(c, 0.0f), (float)(NW - 1));
    const int x0 = (int)floorf(cc);
    lxv[gx] = cc - (float)x0;
    cxv[gx] = x0 - cmin_al;    // x1 = x0+1 implicit (pad col is zero, weight 0)
  }

  float acc = 0.0f;
#pragma unroll
  for (int gy = 0; gy < NGH; ++gy) {
    if (gy >= gh) break;               // block-uniform bound
    const float c = start_h + (float)i * bin_h + ((float)gy + 0.5f) * sub_h;
    const float cc = fminf(fmaxf(c, 0.0f), (float)(NH - 1));
    const int y0 = (int)floorf(cc);
    const float ly = cc - (float)y0;
    const float hy = 1.0f - ly;
    const int ry0 = (y0 - rmin) * S_STRIDE;
    const int ry1 = (min(y0 + 1, NH - 1) - rmin) * S_STRIDE;
#pragma unroll
    for (int gx = 0; gx < NGW; ++gx) {
      if (gx >= gw) break;             // block-uniform bound
      const float lx = lxv[gx];
      const float hx = 1.0f - lx;
      const float* r0 = &S[ry0 + cxv[gx]];
      const float* r1 = &S[ry1 + cxv[gx]];
      const float v00 = r0[0], v01 = r0[1];   // -> ds_read2_b32
      const float v10 = r1[0], v11 = r1[1];   // -> ds_read2_b32
      acc += hy * (hx * v00 + lx * v01) + ly * (hx * v10 + lx * v11);
    }
  }
  pooled[(size_t)n * NK + ch * (NP * NP) + tid] = f2bf(acc * inv_count);
}

// ---------------------------------------------------------------------------
// Kernel 2: bf16 MFMA GEMM  out[1600][768] = A[1600][768] . Bw[768][768]^T + b
// BM=BN=64, BK=64, grid 25x12=300 blocks, 4 waves (2x2), wave tile 32x32.
// Double-buffered LDS, 2-phase prefetch (issue next tile before computing
// current; __syncthreads drains). LDS XOR-swizzle (col16 ^= row&7) applied via
// pre-swizzled GLOBAL source (linear gld_lds dest) + swizzled ds_read addrs:
// kills the 8-way fragment-read bank conflict of the row-major layout.
// ---------------------------------------------------------------------------
#define BM 64
#define BN 64
#define BK 64

static __device__ __forceinline__ void gld_lds16(const unsigned short* g,
                                                 unsigned short* l) {
  __builtin_amdgcn_global_load_lds(
      (const __attribute__((address_space(1))) unsigned int*)g,
      (__attribute__((address_space(3))) unsigned int*)l,
      16, 0, 0);
}

__global__ __launch_bounds__(256) void gemm_kernel(
    const unsigned short* __restrict__ A,    // [1600][768] bf16 (pooled)
    const unsigned short* __restrict__ Bw,   // [768][768]  bf16 (conv_w)
    const float* __restrict__ bias,          // [768]
    float* __restrict__ outp)                // [1600][768] f32
{
  __shared__ __align__(16) unsigned short As[2][BM * BK];   // 2 x 8 KB
  __shared__ __align__(16) unsigned short Bs[2][BM * BK];   // 2 x 8 KB

  const int tid = threadIdx.x;
  const int w = tid >> 6;           // wave 0..3
  const int l = tid & 63;           // lane
  const int bm = blockIdx.x * BM;
  const int bn = blockIdx.y * BN;

  // staging geometry: 512 16B-slots per 64x64 tile; slot s -> row s>>3,
  // col16 s&7. LDS linear; source col16 pre-swizzled with row&7.
  // compute geometry: wave (wr,wc) owns 32x32; lane: lr = l&15, kh = l>>4.
  const int wr = w >> 1, wc = w & 1;
  const int lr = l & 15;
  const int kh = l >> 4;            // 0..3

  const int rA0 = (wr << 5) + lr;   // A-frag rows (mi=0 / mi=1 = +16)
  const int rB0 = (wc << 5) + lr;   // B-frag rows (= C cols)

#define STAGE(buf, kk)                                                       \
  {                                                                          \
    _Pragma("unroll")                                                        \
    for (int q = 0; q < 2; ++q) {                                            \
      const int s   = (q << 8) + tid;                                        \
      const int row = s >> 3;                                                \
      const int c16 = (s & 7) ^ (row & 7);                                   \
      gld_lds16(A  + (size_t)(bm + row) * NK + (kk) + (c16 << 3),            \
                &As[buf][s << 3]);                                           \
      gld_lds16(Bw + (size_t)(bn + row) * NK + (kk) + (c16 << 3),            \
                &Bs[buf][s << 3]);                                           \
    }                                                                        \
  }

  f32x4 acc[2][2] = {};

  STAGE(0, 0)
  __syncthreads();                  // drains vmcnt(0)

  int cur = 0;
  for (int it = 0; it < NK / BK; ++it) {
    if (it + 1 < NK / BK) STAGE(cur ^ 1, (it + 1) * BK)   // overlap w/ compute

#pragma unroll
    for (int ks = 0; ks < 2; ++ks) {
      const int kq = (ks << 2) + kh;                      // k/8 quad index
      const bf16x8 a0 = *reinterpret_cast<const bf16x8*>(
          &As[cur][(rA0 << 6) + ((kq ^ (rA0 & 7)) << 3)]);
      const bf16x8 a1 = *reinterpret_cast<const bf16x8*>(
          &As[cur][((rA0 + 16) << 6) + ((kq ^ (rA0 & 7)) << 3)]);
      const bf16x8 b0 = *reinterpret_cast<const bf16x8*>(
          &Bs[cur][(rB0 << 6) + ((kq ^ (rB0 & 7)) << 3)]);
      const bf16x8 b1 = *reinterpret_cast<const bf16x8*>(
          &Bs[cur][((rB0 + 16) << 6) + ((kq ^ (rB0 & 7)) << 3)]);
      acc[0][0] = __builtin_amdgcn_mfma_f32_16x16x32_bf16(a0, b0, acc[0][0], 0, 0, 0);
      acc[0][1] = __builtin_amdgcn_mfma_f32_16x16x32_bf16(a0, b1, acc[0][1], 0, 0, 0);
      acc[1][0] = __builtin_amdgcn_mfma_f32_16x16x32_bf16(a1, b0, acc[1][0], 0, 0, 0);
      acc[1][1] = __builtin_amdgcn_mfma_f32_16x16x32_bf16(a1, b1, acc[1][1], 0, 0, 0);
    }

    __syncthreads();                // drains vmcnt (next tile landed) + LDS reuse
    cur ^= 1;
  }
#undef STAGE

  // Epilogue: C/D layout col = lane&15, row = (lane>>4)*4 + reg
#pragma unroll
  for (int ni = 0; ni < 2; ++ni) {
    const int col = bn + (wc << 5) + (ni << 4) + lr;
    const float bv = bias[col];
#pragma unroll
    for (int mi = 0; mi < 2; ++mi) {
      const int rbase = bm + (wr << 5) + (mi << 4) + (kh << 2);
#pragma unroll
      for (int q = 0; q < 4; ++q) {
        outp[(size_t)(rbase + q) * ND + col] = acc[mi][ni][q] + bv;
      }
    }
  }
}

extern "C" void kernel_launch(void* const* d_in, const int* in_sizes, int n_in,
                              void* d_out, int out_size, void* d_ws, size_t ws_size,
                              hipStream_t stream) {
  (void)in_sizes; (void)n_in; (void)out_size; (void)ws_size;
  const float* features  = (const float*)d_in[0];
  const float* keypoints = (const float*)d_in[1];
  const float* conv_w    = (const float*)d_in[2];
  const float* conv_b    = (const float*)d_in[3];
  float* outp = (float*)d_out;

  unsigned short* pooled = (unsigned short*)d_ws;                    // 2,457,600 B
  unsigned short* wbf    = (unsigned short*)((char*)d_ws + 2457600); // 1,179,648 B

  pool_convw_kernel<<<NCVW + NTASK, 256, 0, stream>>>(features, keypoints,
                                                      conv_w, pooled, wbf);

  dim3 grid(NKP / BM, ND / BN);   // 25 x 12 = 300
  gemm_kernel<<<grid, 256, 0, stream>>>(pooled, wbf, conv_b, outp);
}